// Round 11
// baseline (139.125 us; speedup 1.0000x reference)
//
#include <hip/hip_runtime.h>
#include <cstdint>

// FCOS post-processor, MI355X — round 11: 4 graph nodes -> 3 via per-image
// last-block-done fusion (producer blocks finish -> 60th/64th block of that
// image runs the consumer phase inline; no spin, per-image overlap).
// Cross-XCD: release = __threadfence() before device atomicAdd; acquire =
// __threadfence() after observing the flag (invalidates stale L2 from the
// previous graph replay — kernel-boundary auto-invalidation is lost by fusion).
//
//  k_init        : zero sdone[16] (tiny custom kernel, NOT a fill node)
//  k_scan_fcr    : A(60 blk/img, 512 thr): read cls+ctr once, 512-bin LDS hist
//                  -> slice; local thresh (suffix>=128) -> prelist u64 keys.
//                  B(last block/img): reduce slices -> exact b*; zero ecnt/edone;
//                  prefill boxes; 2-pass prelist filter -> counting-sort rank
//                  (exact jax top_k order) -> decode+clip -> boxes[rank].
//  k_edges_final : A(64 blk/img, 256 thr): triangular pair IoU>0.6 -> edges.
//                  B(last block/img): rank-sort edges, exact greedy, shfl-scan
//                  select first 100 kept, write dets/labels/fvalid.

#define NIMG 16
#define WW 608
#define HW 243200
#define NF4 60800          // HW/4
#define TOPK 1000
#define NBINS 512
#define NB2 2048           // fine buckets for counting-sort rank
#define SCAN_BLOCKS 60     // per image
#define SCAN_THREADS 512
#define F4_PER_BLOCK 1024  // 60*1024*4 = 245760 >= 243200
#define LS 128             // local-suffix constant for prelist threshold
#define PCAP 1024          // prelist cap per scan block (~136 expected)
#define MCAP 4096          // candidate cap per image (expected ~1035)
#define EBLK 64            // edge blocks per image
#define ECAP 8192          // global edge buffer per image
#define EL_CAP 2048        // LDS edge cap in final phase
#define NPAIR 499500       // TOPK*(TOPK-1)/2
#define NEGV (-1e9f)

__device__ __forceinline__ float sigm(float x) { return 1.0f / (1.0f + expf(-x)); }

__device__ __forceinline__ int binof(float v) {
  if (!(v > 0.0f)) return 0;
  int b = (int)(v * (float)NBINS);
  return b > (NBINS - 1) ? (NBINS - 1) : b;
}

// wave0 (tid<64): *outbs = max b with suffix_bins(b) >= T, else 0.
__device__ __forceinline__ void find_thresh_bin(const unsigned* h, const unsigned* chunk,
                                                unsigned T, unsigned* outbs, int tid) {
  unsigned v = (tid < 32) ? chunk[tid] : 0u;
  unsigned inc = v;
#pragma unroll
  for (int d = 1; d < 32; d <<= 1) {
    unsigned o = __shfl_down(inc, d, 64);
    if (tid + d < 32) inc += o;
  }
  unsigned long long m = __ballot((tid < 32) && (inc >= T));
  if (m == 0ull) { if (tid == 0) *outbs = 0u; return; }
  int cc = 63 - __clzll(m);
  unsigned above = __shfl(inc, cc) - chunk[cc];
  unsigned v2 = (tid < 16) ? h[cc * 16 + tid] : 0u;
  unsigned inc2 = v2;
#pragma unroll
  for (int d = 1; d < 16; d <<= 1) {
    unsigned o = __shfl_down(inc2, d, 64);
    if (tid + d < 16) inc2 += o;
  }
  unsigned long long m2 = __ballot((tid < 16) && (above + inc2 >= T));
  int bb = (m2 != 0ull) ? (63 - __clzll(m2)) : 0;
  if (tid == 0) *outbs = (unsigned)(cc * 16 + bb);
}

__device__ __forceinline__ int bucketof(unsigned long long key, float vmin, float scale) {
  float v = __uint_as_float((unsigned)(key >> 32));
  int b = (int)((v - vmin) * scale);
  return b < 0 ? 0 : (b > NB2 - 1 ? NB2 - 1 : b);
}

__global__ void k_init(unsigned* __restrict__ sdone) {
  if (threadIdx.x < NIMG) sdone[threadIdx.x] = 0u;
}

__global__ __launch_bounds__(SCAN_THREADS) void k_scan_fcr(
    const float4* __restrict__ cls, const float4* __restrict__ ctr,
    unsigned* __restrict__ hist, unsigned long long* __restrict__ pre,
    unsigned* __restrict__ pcnt, unsigned* __restrict__ sdone,
    const float* __restrict__ reg, const int* __restrict__ isz,
    float4* __restrict__ boxes, float* __restrict__ bscores,
    unsigned* __restrict__ ecnt, unsigned* __restrict__ edone) {
  __shared__ unsigned hh[NBINS];                 // A: local hist ; B: reduced hist
  __shared__ unsigned long long bufA64[NB2];     // A: plist(8KB) ; B: hpart then bh+bbase
  __shared__ unsigned long long sk[MCAP];        // B: bucket-sorted keys (32KB)
  __shared__ unsigned chunk[32];
  __shared__ unsigned offs[SCAN_BLOCKS + 1];
  __shared__ unsigned wsum[8];
  __shared__ unsigned sLb, pcl, mc, lastf;
  unsigned* bufA32 = (unsigned*)bufA64;
  const int tid = threadIdx.x;
  const int wid = tid >> 6, lane = tid & 63;
  const int n = blockIdx.y;

  // ---------------- phase A: scan + hist slice + prelist ----------------
  for (int b = tid; b < NBINS; b += SCAN_THREADS) hh[b] = 0u;
  if (tid == 0) pcl = 0u;
  __syncthreads();
  const float4* c4 = cls + (size_t)n * NF4;
  const float4* t4 = ctr + (size_t)n * NF4;
  const int base = blockIdx.x * F4_PER_BLOCK;
  float4 cv[2], tv[2];
  float smr[8];
  bool ok[2];
#pragma unroll
  for (int e = 0; e < 2; ++e) {
    int i = base + e * SCAN_THREADS + tid;
    ok[e] = (i < NF4);
    if (ok[e]) { cv[e] = c4[i]; tv[e] = t4[i]; }
  }
#pragma unroll
  for (int e = 0; e < 2; ++e) {
    const float* cc = (const float*)&cv[e];
    const float* tt = (const float*)&tv[e];
#pragma unroll
    for (int k = 0; k < 4; ++k) {
      float sm = NEGV;
      if (ok[e]) {
        float sc = sigm(cc[k]);
        sm = (sc > 0.05f) ? sc * sigm(tt[k]) : NEGV;
        atomicAdd(&hh[binof(sm)], 1u);  // LDS atomic
      }
      smr[e * 4 + k] = sm;
    }
  }
  __syncthreads();
  if (tid < 32) {
    unsigned s = 0;
    for (int k = 0; k < 16; ++k) s += hh[tid * 16 + k];
    chunk[tid] = s;
  }
  __syncthreads();
  if (tid < 64) find_thresh_bin(hh, chunk, LS, &sLb, tid);
  __syncthreads();
  const unsigned Lb = sLb;
  unsigned long long* plist = bufA64;
#pragma unroll
  for (int e = 0; e < 2; ++e) {
    if (ok[e]) {
#pragma unroll
      for (int k = 0; k < 4; ++k) {
        float sm = smr[e * 4 + k];
        if ((unsigned)binof(sm) >= Lb) {
          unsigned gi = (unsigned)((base + e * SCAN_THREADS + tid) * 4 + k);
          unsigned p = atomicAdd(&pcl, 1u);
          if (p < PCAP)
            plist[p] = ((unsigned long long)__float_as_uint(sm) << 32) |
                       (unsigned long long)(~gi);
        }
      }
    }
  }
  __syncthreads();
  const int bslot = n * SCAN_BLOCKS + blockIdx.x;
  {
    unsigned* gh = hist + (size_t)bslot * NBINS;
    if (tid < NBINS) gh[tid] = hh[tid];
    unsigned m = pcl; if (m > PCAP) m = PCAP;
    unsigned long long* gp = pre + (size_t)bslot * PCAP;
    for (unsigned k = tid; k < m; k += SCAN_THREADS) gp[k] = plist[k];
    if (tid == 0) pcnt[bslot] = m;
  }
  __syncthreads();  // drains all global writes (vmcnt(0) before barrier)
  if (tid == 0) {
    __threadfence();                              // release
    unsigned r = atomicAdd(&sdone[n], 1u);        // device-scope
    lastf = (r == SCAN_BLOCKS - 1) ? 1u : 0u;
  }
  __syncthreads();
  if (!lastf) return;
  __threadfence();  // acquire: invalidate stale cached lines before reading peers' data

  // ---------------- phase B: reduce -> b* -> filter -> counting-sort rank ----------
  if (tid == 0) { mc = 0u; ecnt[n] = 0u; edone[n] = 0u; }
  // reduce 60 slices: hpart[4][128] uint4 in bufA; chunk c covers 15 slices
  {
    uint4* hpart = (uint4*)bufA64;
    const int c = tid >> 7, g = tid & 127;
    const int b0 = c * 15;
    int b1 = b0 + 15; if (b1 > SCAN_BLOCKS) b1 = SCAN_BLOCKS;
    uint4 s = make_uint4(0u, 0u, 0u, 0u);
    const uint4* bse = (const uint4*)(hist + (size_t)n * SCAN_BLOCKS * NBINS);
    for (int b = b0; b < b1; ++b) {
      uint4 v = bse[b * (NBINS / 4) + g];
      s.x += v.x; s.y += v.y; s.z += v.z; s.w += v.w;
    }
    hpart[c * 128 + g] = s;
  }
  // prefill output background
  for (int k = tid; k < TOPK; k += SCAN_THREADS) {
    boxes[n * TOPK + k] = make_float4(0.f, 0.f, 0.f, 0.f);
    bscores[n * TOPK + k] = NEGV;
  }
  __syncthreads();
  if (tid < 128) {
    uint4* hpart = (uint4*)bufA64;
    uint4 s = hpart[tid];
#pragma unroll
    for (int c = 1; c < 4; ++c) {
      uint4 v = hpart[c * 128 + tid];
      s.x += v.x; s.y += v.y; s.z += v.z; s.w += v.w;
    }
    ((uint4*)hh)[tid] = s;
  } else if (tid >= 128 && tid < 192) {  // wave 2: shfl-scan prelist counts
    int l = tid - 128;
    int v = (l < SCAN_BLOCKS) ? (int)pcnt[n * SCAN_BLOCKS + l] : 0;
    int inc = v;
#pragma unroll
    for (int d = 1; d < 64; d <<= 1) {
      int o = __shfl_up(inc, d, 64);
      if (l >= d) inc += o;
    }
    if (l < SCAN_BLOCKS) offs[l + 1] = (unsigned)inc;
    if (l == 0) offs[0] = 0u;
  }
  __syncthreads();
  if (tid < 32) {
    unsigned s = 0;
    for (int k = 0; k < 16; ++k) s += hh[tid * 16 + k];
    chunk[tid] = s;
  }
  __syncthreads();
  if (tid < 64) find_thresh_bin(hh, chunk, TOPK, &sLb, tid);
  // zero bh (bufA32[0..NB2)) for bucket hist
  __syncthreads();
  for (int b = tid; b < NB2; b += SCAN_THREADS) bufA32[b] = 0u;
  __syncthreads();
  const unsigned bs = sLb;
  const unsigned P = offs[SCAN_BLOCKS];
  const unsigned long long* pbase = pre + (size_t)n * SCAN_BLOCKS * PCAP;
  const float vmin = (float)bs * (1.0f / NBINS);
  const float scale = (float)NB2 / fmaxf(1.0f - vmin, 1e-9f);
  unsigned* bh = bufA32;
  unsigned* bbase = bufA32 + NB2;
  // pass 1: filter + bucket hist (no key storage)
  for (unsigned p = tid; p < P; p += SCAN_THREADS) {
    int lo = 0, hi = SCAN_BLOCKS - 1;
    while (lo < hi) {
      int mid = (lo + hi + 1) >> 1;
      if (offs[mid] <= p) lo = mid; else hi = mid - 1;
    }
    unsigned long long key = pbase[(size_t)lo * PCAP + (p - offs[lo])];
    float v = __uint_as_float((unsigned)(key >> 32));
    if ((unsigned)binof(v) >= bs) {
      atomicAdd(&mc, 1u);
      atomicAdd(&bh[bucketof(key, vmin, scale)], 1u);
    }
  }
  __syncthreads();
  // descending bucket bases: 4 consecutive descending-buckets per thread
  {
    int g0 = tid * 4;
    unsigned a0 = bh[NB2 - 1 - g0];
    unsigned a1 = bh[NB2 - 1 - (g0 + 1)];
    unsigned a2 = bh[NB2 - 1 - (g0 + 2)];
    unsigned a3 = bh[NB2 - 1 - (g0 + 3)];
    unsigned ps = a0 + a1 + a2 + a3;
    unsigned inc = ps;
#pragma unroll
    for (int d = 1; d < 64; d <<= 1) {
      unsigned o = __shfl_up(inc, d, 64);
      if (lane >= d) inc += o;
    }
    if (lane == 63) wsum[wid] = inc;
    __syncthreads();
    if (tid < 64) {
      unsigned v = (tid < 8) ? wsum[tid] : 0u;
      unsigned i2 = v;
#pragma unroll
      for (int d = 1; d < 8; d <<= 1) {
        unsigned o = __shfl_up(i2, d, 64);
        if (tid >= d) i2 += o;
      }
      if (tid < 8) wsum[tid] = i2 - v;  // exclusive wave offsets
    }
    __syncthreads();
    unsigned excl = inc - ps + wsum[wid];
    bbase[NB2 - 1 - g0] = excl;
    bbase[NB2 - 1 - (g0 + 1)] = excl + a0;
    bbase[NB2 - 1 - (g0 + 2)] = excl + a0 + a1;
    bbase[NB2 - 1 - (g0 + 3)] = excl + a0 + a1 + a2;
  }
  __syncthreads();
  for (int b = tid; b < NB2; b += SCAN_THREADS) bh[b] = 0u;  // scatter counters
  __syncthreads();
  // pass 2: filter + scatter into bucket-sorted sk
  for (unsigned p = tid; p < P; p += SCAN_THREADS) {
    int lo = 0, hi = SCAN_BLOCKS - 1;
    while (lo < hi) {
      int mid = (lo + hi + 1) >> 1;
      if (offs[mid] <= p) lo = mid; else hi = mid - 1;
    }
    unsigned long long key = pbase[(size_t)lo * PCAP + (p - offs[lo])];
    float v = __uint_as_float((unsigned)(key >> 32));
    if ((unsigned)binof(v) >= bs) {
      int b = bucketof(key, vmin, scale);
      unsigned pos = bbase[b] + atomicAdd(&bh[b], 1u);
      if (pos < MCAP) sk[pos] = key;
    }
  }
  __syncthreads();
  const unsigned M = (mc > MCAP) ? MCAP : mc;
  // exact rank = bucket base + #{same-bucket keys > mine}; decode winners
  const float wmax = (float)(isz[n * 2 + 1] - 1);
  const float hmax = (float)(isz[n * 2 + 0] - 1);
  const float* rg = reg + (size_t)n * 4 * HW;
  for (unsigned s = tid; s < M; s += SCAN_THREADS) {
    const unsigned long long mykey = sk[s];
    int b = bucketof(mykey, vmin, scale);
    unsigned beg = bbase[b];
    unsigned end = (b > 0) ? bbase[b - 1] : M;
    if (end > M) end = M;
    unsigned rank = beg;
    for (unsigned t = beg; t < end; ++t) rank += (sk[t] > mykey) ? 1u : 0u;
    if (rank >= TOPK) continue;
    const unsigned gi = ~(unsigned)(mykey & 0xFFFFFFFFull);
    const float val = __uint_as_float((unsigned)(mykey >> 32));
    int wx = (int)gi % WW, hy = (int)gi / WW;
    float lx = (float)(wx * 8 + 4), ly = (float)(hy * 8 + 4);
    float l = rg[0 * HW + gi], tt = rg[1 * HW + gi];
    float rr = rg[2 * HW + gi], bb2 = rg[3 * HW + gi];
    float x1 = lx - l, y1 = ly - tt, x2 = lx + rr, y2 = ly + bb2;
    x1 = fminf(fmaxf(x1, 0.0f), wmax);
    x2 = fminf(fmaxf(x2, 0.0f), wmax);
    y1 = fminf(fmaxf(y1, 0.0f), hmax);
    y2 = fminf(fmaxf(y2, 0.0f), hmax);
    float scr = val;
    if (!(((x2 - x1 + 1.0f) >= 0.0f) && ((y2 - y1 + 1.0f) >= 0.0f))) scr = NEGV;
    boxes[n * TOPK + rank] = make_float4(x1, y1, x2, y2);
    bscores[n * TOPK + rank] = scr;
  }
}

__global__ __launch_bounds__(256) void k_edges_final(
    const float4* __restrict__ boxes, const float* __restrict__ bscores,
    unsigned* __restrict__ ecnt, unsigned* __restrict__ edges,
    unsigned* __restrict__ edone, float* __restrict__ out) {
  __shared__ float4 sb[TOPK];
  __shared__ float saz[TOPK];  // valid ? area : -1
  __shared__ unsigned eds[EL_CAP], eds2[EL_CAP];
  __shared__ unsigned char kept[TOPK];
  __shared__ int sel[100];
  __shared__ unsigned lastf;
  const int n = blockIdx.y;
  const int tid = threadIdx.x;
  // ---------------- phase A: triangular pair IoU -> edge list ----------------
  for (int k = tid; k < TOPK; k += 256) {
    float4 b = boxes[n * TOPK + k];
    sb[k] = b;
    float sc = bscores[n * TOPK + k];
    saz[k] = (sc > NEGV * 0.5f) ? (b.z - b.x) * (b.w - b.y) : -1.0f;
  }
  __syncthreads();
  for (unsigned q = blockIdx.x * 256u + (unsigned)tid; q < NPAIR; q += EBLK * 256u) {
    unsigned j = (unsigned)(0.5f * (1.0f + sqrtf(1.0f + 8.0f * (float)q)));
    while (j * (j - 1u) / 2u > q) --j;
    while ((j + 1u) * j / 2u <= q) ++j;
    unsigned i = q - j * (j - 1u) / 2u;  // 0 <= i < j < TOPK
    float ai = saz[i], aj = saz[j];
    if (ai < 0.0f || aj < 0.0f) continue;
    float4 bi = sb[i], bj = sb[j];
    float ltx = fmaxf(bi.x, bj.x), lty = fmaxf(bi.y, bj.y);
    float rbx = fminf(bi.z, bj.z), rby = fminf(bi.w, bj.w);
    float wv = fmaxf(rbx - ltx, 0.0f), hv = fmaxf(rby - lty, 0.0f);
    float inter = wv * hv;
    float iou = inter / (ai + aj - inter + 1e-9f);
    if (iou > 0.6f) {
      unsigned pos = atomicAdd(&ecnt[n], 1u);  // device atomic, rare (~15/image)
      if (pos < ECAP) edges[n * ECAP + pos] = (i << 10) | j;
    }
  }
  __syncthreads();
  if (tid == 0) {
    __threadfence();                           // release
    unsigned r = atomicAdd(&edone[n], 1u);
    lastf = (r == EBLK - 1) ? 1u : 0u;
  }
  __syncthreads();
  if (!lastf) return;
  __threadfence();  // acquire

  // ---------------- phase B: exact greedy NMS + select + write ----------------
  unsigned E = ecnt[n]; if (E > EL_CAP) E = EL_CAP;
  for (int k = tid; k < TOPK; k += 256) kept[k] = 1;
  for (int e = tid; e < (int)E; e += 256) eds[e] = edges[n * ECAP + e];
  if (tid < 100) sel[tid] = -1;
  __syncthreads();
  // parallel sort (unique keys): position = #{smaller}; ascending = greedy order
  for (int e = tid; e < (int)E; e += 256) {
    unsigned v = eds[e];
    unsigned r = 0;
    for (unsigned t = 0; t < E; ++t) r += (eds[t] < v) ? 1u : 0u;
    eds2[r] = v;
  }
  __syncthreads();
  if (tid == 0) {  // exact greedy: kept[i] final before any edge (i,*) applied
    for (int e = 0; e < (int)E; ++e) {
      unsigned i = eds2[e] >> 10, j = eds2[e] & 1023u;
      if (kept[i]) kept[j] = 0;
    }
  }
  __syncthreads();
  // wave 0: chunk counts + shfl exclusive scan + select first 100 kept
  if (tid < 64) {
    int c0 = tid * 16;
    int c1 = c0 + 16; if (c1 > TOPK) c1 = TOPK;
    int cnt = 0;
    for (int e = c0; e < c1; ++e)
      if (kept[e] && saz[e] >= 0.0f) cnt++;
    int inc = cnt;
#pragma unroll
    for (int d = 1; d < 64; d <<= 1) {
      int o = __shfl_up(inc, d, 64);
      if (tid >= d) inc += o;
    }
    unsigned r = (unsigned)(inc - cnt);
    for (int e = c0; e < c1; ++e) {
      if (kept[e] && saz[e] >= 0.0f) {
        if (r < 100u) sel[r] = e;
        r++;
      }
    }
  }
  __syncthreads();
  for (int k = tid; k < 100; k += 256) {
    int s = sel[k];
    float x1 = 0.f, y1 = 0.f, x2 = 0.f, y2 = 0.f, sc = 0.f, lab = 0.f, fv = 0.f;
    if (s >= 0) {
      float4 b = sb[s];
      x1 = b.x; y1 = b.y; x2 = b.z; y2 = b.w;
      sc = bscores[n * TOPK + s]; lab = 1.0f; fv = 1.0f;
    }
    int o = (n * 100 + k) * 5;
    out[o + 0] = x1; out[o + 1] = y1; out[o + 2] = x2; out[o + 3] = y2; out[o + 4] = sc;
    out[NIMG * 500 + n * 100 + k] = lab;
    out[NIMG * 600 + n * 100 + k] = fv;
  }
}

extern "C" void kernel_launch(void* const* d_in, const int* in_sizes, int n_in,
                              void* d_out, int out_size, void* d_ws, size_t ws_size,
                              hipStream_t stream) {
  // inputs: 0=locations (unused), 1=box_cls, 2=box_regression, 3=centerness, 4=image_sizes
  const float4* cls4 = (const float4*)d_in[1];
  const float* reg = (const float*)d_in[2];
  const float4* ctr4 = (const float4*)d_in[3];
  const int* isz = (const int*)d_in[4];
  float* out = (float*)d_out;
  uint8_t* w = (uint8_t*)d_ws;

  uint8_t* p = w;
  unsigned long long* pre = (unsigned long long*)p; p += (size_t)NIMG * SCAN_BLOCKS * PCAP * 8; // 7.9 MB
  unsigned* hist = (unsigned*)p;   p += (size_t)NIMG * SCAN_BLOCKS * NBINS * 4;                 // 2 MB
  float* boxes = (float*)p;        p += (size_t)NIMG * TOPK * 16;
  float* bscores = (float*)p;      p += (size_t)NIMG * TOPK * 4;
  unsigned* edges = (unsigned*)p;  p += (size_t)NIMG * ECAP * 4;
  unsigned* pcnt = (unsigned*)p;   p += (size_t)NIMG * SCAN_BLOCKS * 4;
  unsigned* sdone = (unsigned*)p;  p += 64;
  unsigned* edone = (unsigned*)p;  p += 64;
  unsigned* ecnt = (unsigned*)p;   p += 64;
  (void)ws_size;  // ~10.8 MB needed

  k_init<<<1, 64, 0, stream>>>(sdone);
  dim3 g1(SCAN_BLOCKS, NIMG);
  k_scan_fcr<<<g1, SCAN_THREADS, 0, stream>>>(cls4, ctr4, hist, pre, pcnt, sdone,
                                              reg, isz, (float4*)boxes, bscores,
                                              ecnt, edone);
  dim3 g2(EBLK, NIMG);
  k_edges_final<<<g2, 256, 0, stream>>>((const float4*)boxes, bscores, ecnt, edges,
                                        edone, out);
}

// Round 12
// 75.959 us; speedup vs baseline: 1.8316x; 1.8316x over previous
//
#include <hip/hip_runtime.h>
#include <cstdint>

// FCOS post-processor, MI355X — round 12.
// R11 postmortem: fusing scan+fcr cost 960 per-block release __threadfence()
// (L2 writeback storms on non-coherent XCD L2s) and carried phase B's 50KB LDS
// in every scan block (3 blk/CU, 336K bank conflicts) -> 110us. The edges+final
// fusion (1024 blocks, small phase B) was NOT the bottleneck and passed.
// R12 = R10's proven k_scanstore + k_fcr (separate, no fences) + R11's fused
// k_edges_final. 3 graph nodes, no init node (k_fcr zeroes ecnt/edone).
//
//  k_scanstore   : read cls+ctr once (31 MB). Per block: 512-bin LDS hist ->
//                  slice; local thresh (suffix>=128) -> prelist u64 keys.
//  k_fcr         : per image (1024 thr): reduce slices -> exact b*; filter
//                  prelists -> keys[M]; counting-sort rank (exact jax top_k
//                  order); decode+clip -> boxes[rank]; zero ecnt/edone.
//  k_edges_final : A(64 blk/img): triangular pair IoU>0.6 -> edge list.
//                  B(last block/img): rank-sort edges, exact greedy, shfl-scan
//                  select first 100 kept, write dets/labels/fvalid.

#define NIMG 16
#define WW 608
#define HW 243200
#define NF4 60800          // HW/4
#define TOPK 1000
#define NBINS 512
#define NB2 2048           // fine buckets for counting-sort rank
#define SCAN_BLOCKS 60     // per image
#define SCAN_THREADS 256
#define F4_PER_BLOCK 1024  // 60*1024*4 = 245760 >= 243200
#define LS 128             // local-suffix constant for prelist threshold
#define PCAP 1024          // prelist cap per scan block (~136 expected)
#define MCAP 4096          // candidate cap per image (expected ~1035)
#define EBLK 64            // edge blocks per image
#define ECAP 8192          // global edge buffer per image
#define EL_CAP 2048        // LDS edge cap in final phase
#define NPAIR 499500       // TOPK*(TOPK-1)/2
#define NEGV (-1e9f)

__device__ __forceinline__ float sigm(float x) { return 1.0f / (1.0f + expf(-x)); }

__device__ __forceinline__ int binof(float v) {
  if (!(v > 0.0f)) return 0;
  int b = (int)(v * (float)NBINS);
  return b > (NBINS - 1) ? (NBINS - 1) : b;
}

// wave0 (tid<64): *outbs = max b with suffix_bins(b) >= T, else 0.
__device__ __forceinline__ void find_thresh_bin(const unsigned* h, const unsigned* chunk,
                                                unsigned T, unsigned* outbs, int tid) {
  unsigned v = (tid < 32) ? chunk[tid] : 0u;
  unsigned inc = v;
#pragma unroll
  for (int d = 1; d < 32; d <<= 1) {
    unsigned o = __shfl_down(inc, d, 64);
    if (tid + d < 32) inc += o;
  }
  unsigned long long m = __ballot((tid < 32) && (inc >= T));
  if (m == 0ull) { if (tid == 0) *outbs = 0u; return; }
  int cc = 63 - __clzll(m);
  unsigned above = __shfl(inc, cc) - chunk[cc];
  unsigned v2 = (tid < 16) ? h[cc * 16 + tid] : 0u;
  unsigned inc2 = v2;
#pragma unroll
  for (int d = 1; d < 16; d <<= 1) {
    unsigned o = __shfl_down(inc2, d, 64);
    if (tid + d < 16) inc2 += o;
  }
  unsigned long long m2 = __ballot((tid < 16) && (above + inc2 >= T));
  int bb = (m2 != 0ull) ? (63 - __clzll(m2)) : 0;
  if (tid == 0) *outbs = (unsigned)(cc * 16 + bb);
}

__device__ __forceinline__ int bucketof(unsigned long long key, float vmin, float scale) {
  float v = __uint_as_float((unsigned)(key >> 32));
  int b = (int)((v - vmin) * scale);
  return b < 0 ? 0 : (b > NB2 - 1 ? NB2 - 1 : b);
}

__global__ __launch_bounds__(SCAN_THREADS) void k_scanstore(
    const float4* __restrict__ cls, const float4* __restrict__ ctr,
    unsigned* __restrict__ hist, unsigned long long* __restrict__ pre,
    unsigned* __restrict__ pcnt) {
  __shared__ unsigned lh[NBINS];
  __shared__ unsigned long long plist[PCAP];
  __shared__ unsigned chunk[NBINS / 16];
  __shared__ unsigned sLb, pcl;
  const int tid = threadIdx.x;
  for (int b = tid; b < NBINS; b += SCAN_THREADS) lh[b] = 0u;
  if (tid == 0) pcl = 0u;
  __syncthreads();
  const int n = blockIdx.y;
  const float4* c4 = cls + (size_t)n * NF4;
  const float4* t4 = ctr + (size_t)n * NF4;
  const int base = blockIdx.x * F4_PER_BLOCK;
  float4 cv[4], tv[4];
  float smr[16];
  bool ok[4];
#pragma unroll
  for (int e = 0; e < 4; ++e) {
    int i = base + e * SCAN_THREADS + tid;
    ok[e] = (i < NF4);
    if (ok[e]) { cv[e] = c4[i]; tv[e] = t4[i]; }
  }
#pragma unroll
  for (int e = 0; e < 4; ++e) {
    const float* cc = (const float*)&cv[e];
    const float* tt = (const float*)&tv[e];
#pragma unroll
    for (int k = 0; k < 4; ++k) {
      float sm = NEGV;
      if (ok[e]) {
        float sc = sigm(cc[k]);
        sm = (sc > 0.05f) ? sc * sigm(tt[k]) : NEGV;
        atomicAdd(&lh[binof(sm)], 1u);  // LDS atomic
      }
      smr[e * 4 + k] = sm;
    }
  }
  __syncthreads();
  if (tid < NBINS / 16) {
    unsigned s = 0;
    for (int k = 0; k < 16; ++k) s += lh[tid * 16 + k];
    chunk[tid] = s;
  }
  __syncthreads();
  if (tid < 64) find_thresh_bin(lh, chunk, LS, &sLb, tid);
  __syncthreads();
  const unsigned Lb = sLb;
#pragma unroll
  for (int e = 0; e < 4; ++e) {
    if (ok[e]) {
#pragma unroll
      for (int k = 0; k < 4; ++k) {
        float sm = smr[e * 4 + k];
        if ((unsigned)binof(sm) >= Lb) {
          unsigned gi = (unsigned)((base + e * SCAN_THREADS + tid) * 4 + k);
          unsigned p = atomicAdd(&pcl, 1u);  // LDS atomic
          if (p < PCAP)
            plist[p] = ((unsigned long long)__float_as_uint(sm) << 32) |
                       (unsigned long long)(~gi);
        }
      }
    }
  }
  __syncthreads();
  const int bslot = n * SCAN_BLOCKS + blockIdx.x;
  unsigned* gh = hist + (size_t)bslot * NBINS;
  for (int b = tid; b < NBINS; b += SCAN_THREADS) gh[b] = lh[b];
  unsigned m = pcl; if (m > PCAP) m = PCAP;
  unsigned long long* gp = pre + (size_t)bslot * PCAP;
  for (unsigned k = tid; k < m; k += SCAN_THREADS) gp[k] = plist[k];
  if (tid == 0) pcnt[bslot] = m;
}

// findcollect + counting-sort rank fused: one 1024-thread block per image.
__global__ __launch_bounds__(1024) void k_fcr(
    const unsigned* __restrict__ hist, const unsigned long long* __restrict__ pre,
    const unsigned* __restrict__ pcnt,
    const float* __restrict__ reg, const int* __restrict__ isz,
    float4* __restrict__ boxes, float* __restrict__ bscores,
    unsigned* __restrict__ ecnt, unsigned* __restrict__ edone) {
  __shared__ uint4 hpart[8][NBINS / 4];  // 16 KB partials
  __shared__ unsigned h[NBINS];
  __shared__ unsigned chunk[NBINS / 16];
  __shared__ unsigned offs[SCAN_BLOCKS + 1];
  __shared__ unsigned long long keysl[MCAP];
  __shared__ unsigned long long sk[MCAP];  // bucket-sorted keys
  __shared__ unsigned bh[NB2];             // bucket hist / scatter counters
  __shared__ unsigned bbase[NB2];          // descending-order bucket base
  __shared__ unsigned wsum[16];
  __shared__ unsigned sBs, mc;
  const int n = blockIdx.x;
  const int tid = threadIdx.x;
  const int wid = tid >> 6, lane = tid & 63;
  // slice reduce, all 1024 threads: c=tid>>7 handles 8 slices, g=tid&127 group
  {
    const int c = tid >> 7, g = tid & 127;
    const int b0 = c * 8;
    int b1 = b0 + 8; if (b1 > SCAN_BLOCKS) b1 = SCAN_BLOCKS;
    uint4 s = make_uint4(0u, 0u, 0u, 0u);
    const uint4* bse = (const uint4*)(hist + (size_t)n * SCAN_BLOCKS * NBINS);
    for (int b = b0; b < b1; ++b) {
      uint4 v = bse[b * (NBINS / 4) + g];
      s.x += v.x; s.y += v.y; s.z += v.z; s.w += v.w;
    }
    hpart[c][g] = s;
  }
  if (tid == 0) { mc = 0u; ecnt[n] = 0u; edone[n] = 0u; }
  // prefill output background (rank phase overwrites ranks < min(M,TOPK))
  for (int k = tid; k < TOPK; k += 1024) {
    boxes[n * TOPK + k] = make_float4(0.f, 0.f, 0.f, 0.f);
    bscores[n * TOPK + k] = NEGV;
  }
  __syncthreads();
  if (tid < 128) {  // final hist sum
    uint4 s = make_uint4(0u, 0u, 0u, 0u);
#pragma unroll
    for (int c = 0; c < 8; ++c) {
      uint4 v = hpart[c][tid];
      s.x += v.x; s.y += v.y; s.z += v.z; s.w += v.w;
    }
    ((uint4*)h)[tid] = s;
  } else if (tid >= 128 && tid < 192) {  // wave 2: shfl-scan prelist counts
    int l = tid - 128;
    int v = (l < SCAN_BLOCKS) ? (int)pcnt[n * SCAN_BLOCKS + l] : 0;
    int inc = v;
#pragma unroll
    for (int d = 1; d < 64; d <<= 1) {
      int o = __shfl_up(inc, d, 64);
      if (l >= d) inc += o;
    }
    if (l < SCAN_BLOCKS) offs[l + 1] = (unsigned)inc;
    if (l == 0) offs[0] = 0u;
  }
  __syncthreads();
  if (tid < NBINS / 16) {
    unsigned s = 0;
    for (int k = 0; k < 16; ++k) s += h[tid * 16 + k];
    chunk[tid] = s;
  }
  __syncthreads();
  if (tid < 64) find_thresh_bin(h, chunk, TOPK, &sBs, tid);
  __syncthreads();
  const unsigned bs = sBs;
  const unsigned P = offs[SCAN_BLOCKS];
  const unsigned long long* pbase = pre + (size_t)n * SCAN_BLOCKS * PCAP;
  for (unsigned p = tid; p < P; p += 1024) {
    int lo = 0, hi = SCAN_BLOCKS - 1;  // find b: offs[b] <= p < offs[b+1]
    while (lo < hi) {
      int mid = (lo + hi + 1) >> 1;
      if (offs[mid] <= p) lo = mid; else hi = mid - 1;
    }
    unsigned long long key = pbase[(size_t)lo * PCAP + (p - offs[lo])];
    float v = __uint_as_float((unsigned)(key >> 32));
    if ((unsigned)binof(v) >= bs) {
      unsigned q = atomicAdd(&mc, 1u);  // LDS atomic
      if (q < MCAP) keysl[q] = key;
    }
  }
  for (int b = tid; b < NB2; b += 1024) bh[b] = 0u;
  __syncthreads();
  const unsigned M = (mc > MCAP) ? MCAP : mc;
  // candidates have binof(val) >= bs => val >= bs/512 => monotone bucket map
  const float vmin = (float)bs * (1.0f / NBINS);
  const float scale = (float)NB2 / fmaxf(1.0f - vmin, 1e-9f);
  // 1) bucket histogram
  for (unsigned c = tid; c < M; c += 1024)
    atomicAdd(&bh[bucketof(keysl[c], vmin, scale)], 1u);
  __syncthreads();
  // 2) descending bucket bases: bbase[b] = #keys in buckets > b
  {
    int g0 = tid * 2, g1 = g0 + 1;
    unsigned a0 = bh[NB2 - 1 - g0];
    unsigned a1 = bh[NB2 - 1 - g1];
    unsigned pair = a0 + a1;
    unsigned inc = pair;
#pragma unroll
    for (int d = 1; d < 64; d <<= 1) {
      unsigned o = __shfl_up(inc, d, 64);
      if (lane >= d) inc += o;
    }
    if (lane == 63) wsum[wid] = inc;
    __syncthreads();
    if (tid < 64) {
      unsigned v = (tid < 16) ? wsum[tid] : 0u;
      unsigned i2 = v;
#pragma unroll
      for (int d = 1; d < 16; d <<= 1) {
        unsigned o = __shfl_up(i2, d, 64);
        if (tid >= d) i2 += o;
      }
      if (tid < 16) wsum[tid] = i2 - v;  // exclusive wave offsets
    }
    __syncthreads();
    unsigned excl = inc - pair + wsum[wid];
    bbase[NB2 - 1 - g0] = excl;
    bbase[NB2 - 1 - g1] = excl + a0;
  }
  __syncthreads();
  for (int b = tid; b < NB2; b += 1024) bh[b] = 0u;  // reuse as scatter counters
  __syncthreads();
  // 3) scatter into bucket-sorted order
  for (unsigned c = tid; c < M; c += 1024) {
    unsigned long long key = keysl[c];
    int b = bucketof(key, vmin, scale);
    unsigned pos = bbase[b] + atomicAdd(&bh[b], 1u);
    if (pos < MCAP) sk[pos] = key;
  }
  __syncthreads();
  // 4) exact rank = bucket base + #{same-bucket keys > mine}; decode winners
  const float wmax = (float)(isz[n * 2 + 1] - 1);
  const float hmax = (float)(isz[n * 2 + 0] - 1);
  const float* rg = reg + (size_t)n * 4 * HW;
  for (unsigned s = tid; s < M; s += 1024) {
    const unsigned long long mykey = sk[s];
    int b = bucketof(mykey, vmin, scale);
    unsigned beg = bbase[b];
    unsigned end = (b > 0) ? bbase[b - 1] : M;
    if (end > M) end = M;
    unsigned rank = beg;
    for (unsigned t = beg; t < end; ++t) rank += (sk[t] > mykey) ? 1u : 0u;
    if (rank >= TOPK) continue;
    const unsigned gi = ~(unsigned)(mykey & 0xFFFFFFFFull);
    const float val = __uint_as_float((unsigned)(mykey >> 32));
    int wx = (int)gi % WW, hy = (int)gi / WW;
    float lx = (float)(wx * 8 + 4), ly = (float)(hy * 8 + 4);
    float l = rg[0 * HW + gi], tt = rg[1 * HW + gi];
    float rr = rg[2 * HW + gi], bb2 = rg[3 * HW + gi];
    float x1 = lx - l, y1 = ly - tt, x2 = lx + rr, y2 = ly + bb2;
    x1 = fminf(fmaxf(x1, 0.0f), wmax);
    x2 = fminf(fmaxf(x2, 0.0f), wmax);
    y1 = fminf(fmaxf(y1, 0.0f), hmax);
    y2 = fminf(fmaxf(y2, 0.0f), hmax);
    float scr = val;
    if (!(((x2 - x1 + 1.0f) >= 0.0f) && ((y2 - y1 + 1.0f) >= 0.0f))) scr = NEGV;
    boxes[n * TOPK + rank] = make_float4(x1, y1, x2, y2);
    bscores[n * TOPK + rank] = scr;
  }
}

// edges (phase A, 64 blk/img) + final NMS/select/write (phase B, last block/img)
__global__ __launch_bounds__(256) void k_edges_final(
    const float4* __restrict__ boxes, const float* __restrict__ bscores,
    unsigned* __restrict__ ecnt, unsigned* __restrict__ edges,
    unsigned* __restrict__ edone, float* __restrict__ out) {
  __shared__ float4 sb[TOPK];
  __shared__ float saz[TOPK];  // valid ? area : -1
  __shared__ unsigned eds[EL_CAP], eds2[EL_CAP];
  __shared__ unsigned char kept[TOPK];
  __shared__ int sel[100];
  __shared__ unsigned lastf;
  const int n = blockIdx.y;
  const int tid = threadIdx.x;
  // ---------------- phase A: triangular pair IoU -> edge list ----------------
  for (int k = tid; k < TOPK; k += 256) {
    float4 b = boxes[n * TOPK + k];
    sb[k] = b;
    float sc = bscores[n * TOPK + k];
    saz[k] = (sc > NEGV * 0.5f) ? (b.z - b.x) * (b.w - b.y) : -1.0f;
  }
  __syncthreads();
  for (unsigned q = blockIdx.x * 256u + (unsigned)tid; q < NPAIR; q += EBLK * 256u) {
    unsigned j = (unsigned)(0.5f * (1.0f + sqrtf(1.0f + 8.0f * (float)q)));
    while (j * (j - 1u) / 2u > q) --j;
    while ((j + 1u) * j / 2u <= q) ++j;
    unsigned i = q - j * (j - 1u) / 2u;  // 0 <= i < j < TOPK
    float ai = saz[i], aj = saz[j];
    if (ai < 0.0f || aj < 0.0f) continue;
    float4 bi = sb[i], bj = sb[j];
    float ltx = fmaxf(bi.x, bj.x), lty = fmaxf(bi.y, bj.y);
    float rbx = fminf(bi.z, bj.z), rby = fminf(bi.w, bj.w);
    float wv = fmaxf(rbx - ltx, 0.0f), hv = fmaxf(rby - lty, 0.0f);
    float inter = wv * hv;
    float iou = inter / (ai + aj - inter + 1e-9f);
    if (iou > 0.6f) {
      unsigned pos = atomicAdd(&ecnt[n], 1u);  // device atomic, rare (~15/image)
      if (pos < ECAP) edges[n * ECAP + pos] = (i << 10) | j;
    }
  }
  __syncthreads();
  if (tid == 0) {
    __threadfence();                           // release
    unsigned r = atomicAdd(&edone[n], 1u);
    lastf = (r == EBLK - 1) ? 1u : 0u;
  }
  __syncthreads();
  if (!lastf) return;
  __threadfence();  // acquire: invalidate stale lines before reading peers' edges

  // ---------------- phase B: exact greedy NMS + select + write ----------------
  unsigned E = ecnt[n]; if (E > EL_CAP) E = EL_CAP;
  for (int k = tid; k < TOPK; k += 256) kept[k] = 1;
  for (int e = tid; e < (int)E; e += 256) eds[e] = edges[n * ECAP + e];
  if (tid < 100) sel[tid] = -1;
  __syncthreads();
  // parallel sort (unique keys): position = #{smaller}; ascending = greedy order
  for (int e = tid; e < (int)E; e += 256) {
    unsigned v = eds[e];
    unsigned r = 0;
    for (unsigned t = 0; t < E; ++t) r += (eds[t] < v) ? 1u : 0u;
    eds2[r] = v;
  }
  __syncthreads();
  if (tid == 0) {  // exact greedy: kept[i] final before any edge (i,*) applied
    for (int e = 0; e < (int)E; ++e) {
      unsigned i = eds2[e] >> 10, j = eds2[e] & 1023u;
      if (kept[i]) kept[j] = 0;
    }
  }
  __syncthreads();
  // wave 0: chunk counts + shfl exclusive scan + select first 100 kept
  if (tid < 64) {
    int c0 = tid * 16;
    int c1 = c0 + 16; if (c1 > TOPK) c1 = TOPK;
    int cnt = 0;
    for (int e = c0; e < c1; ++e)
      if (kept[e] && saz[e] >= 0.0f) cnt++;
    int inc = cnt;
#pragma unroll
    for (int d = 1; d < 64; d <<= 1) {
      int o = __shfl_up(inc, d, 64);
      if (tid >= d) inc += o;
    }
    unsigned r = (unsigned)(inc - cnt);
    for (int e = c0; e < c1; ++e) {
      if (kept[e] && saz[e] >= 0.0f) {
        if (r < 100u) sel[r] = e;
        r++;
      }
    }
  }
  __syncthreads();
  for (int k = tid; k < 100; k += 256) {
    int s = sel[k];
    float x1 = 0.f, y1 = 0.f, x2 = 0.f, y2 = 0.f, sc = 0.f, lab = 0.f, fv = 0.f;
    if (s >= 0) {
      float4 b = sb[s];
      x1 = b.x; y1 = b.y; x2 = b.z; y2 = b.w;
      sc = bscores[n * TOPK + s]; lab = 1.0f; fv = 1.0f;
    }
    int o = (n * 100 + k) * 5;
    out[o + 0] = x1; out[o + 1] = y1; out[o + 2] = x2; out[o + 3] = y2; out[o + 4] = sc;
    out[NIMG * 500 + n * 100 + k] = lab;
    out[NIMG * 600 + n * 100 + k] = fv;
  }
}

extern "C" void kernel_launch(void* const* d_in, const int* in_sizes, int n_in,
                              void* d_out, int out_size, void* d_ws, size_t ws_size,
                              hipStream_t stream) {
  // inputs: 0=locations (unused), 1=box_cls, 2=box_regression, 3=centerness, 4=image_sizes
  const float4* cls4 = (const float4*)d_in[1];
  const float* reg = (const float*)d_in[2];
  const float4* ctr4 = (const float4*)d_in[3];
  const int* isz = (const int*)d_in[4];
  float* out = (float*)d_out;
  uint8_t* w = (uint8_t*)d_ws;

  uint8_t* p = w;
  unsigned long long* pre = (unsigned long long*)p; p += (size_t)NIMG * SCAN_BLOCKS * PCAP * 8; // 7.9 MB
  unsigned* hist = (unsigned*)p;   p += (size_t)NIMG * SCAN_BLOCKS * NBINS * 4;                 // 2 MB
  float* boxes = (float*)p;        p += (size_t)NIMG * TOPK * 16;
  float* bscores = (float*)p;      p += (size_t)NIMG * TOPK * 4;
  unsigned* edges = (unsigned*)p;  p += (size_t)NIMG * ECAP * 4;
  unsigned* pcnt = (unsigned*)p;   p += (size_t)NIMG * SCAN_BLOCKS * 4;
  unsigned* ecnt = (unsigned*)p;   p += 64;
  unsigned* edone = (unsigned*)p;  p += 64;
  (void)ws_size;  // ~10.8 MB needed

  dim3 g1(SCAN_BLOCKS, NIMG);
  k_scanstore<<<g1, SCAN_THREADS, 0, stream>>>(cls4, ctr4, hist, pre, pcnt);
  k_fcr<<<NIMG, 1024, 0, stream>>>(hist, pre, pcnt, reg, isz, (float4*)boxes, bscores,
                                   ecnt, edone);
  dim3 g2(EBLK, NIMG);
  k_edges_final<<<g2, 256, 0, stream>>>((const float4*)boxes, bscores, ecnt, edges,
                                        edone, out);
}